// Round 11
// baseline (173.194 us; speedup 1.0000x reference)
//
#include <hip/hip_runtime.h>

// LSTM_WP: B=4096 batch-1 LSTMs, T=H=128, input_size=1, fused MFMA-f16 recurrence.
// Round 11: the last untested design-matrix cell — TWO CO-RESIDENT BLOCKS PER CU
// WITH ZERO DUPLICATION. BLOCK=256 (4 waves), each wave owns 2 column tiles
// (32 gate-cols, 32 MFMAs/step, 128-VGPR weights); 256 blocks -> 2 blocks/CU,
// so each SIMD hosts 2 waves from DIFFERENT blocks with independent barriers:
// when block A drains at s_barrier, block B's wave issues. Per-SIMD pipe totals
// are byte-identical to r8 (620 cyc matrix + ~670 VALU, zero dup, full chip).
// Bonus: A-fragment (h) shared by both tiles -> per-CU LDS read traffic halves.
// r10 lesson: within-wave arrangement is neutral -> plain 4-deep chains, no
// preact shadow (saves regs; budget ~230 of 256).

#define H   128
#define T   128
#define BLOCK 256
#define HSTRIDE 136     // f16 per h row: 272 B -> b128-aligned, 2-way banks (free)
#define XSTRIDE 20      // f32 per xs row: 80 B, b128-aligned float4 reads
#define LOG2E    1.44269504088896340736f
#define TWOLOG2E 2.88539008177792681472f

typedef _Float16 f16x8 __attribute__((ext_vector_type(8)));
typedef float    f32x4 __attribute__((ext_vector_type(4)));

// ---- prep: W_hh f32 [512][128] -> f16 fragment-contiguous, log2e-pre-scaled ----
// layout: idx(ct,g,kc,q,l15) = (((ct*4+g)*4+kc)*4+q)*16+l15, 8 f16 each (16 B).
__global__ void prep_whh_kernel(const float* __restrict__ W_hh, _Float16* __restrict__ wfrag)
{
    int idx = blockIdx.x * blockDim.x + threadIdx.x;     // 0..8191
    int l15 =  idx        & 15;
    int q   = (idx >> 4)  & 3;
    int kc  = (idx >> 6)  & 3;
    int g   = (idx >> 8)  & 3;
    int ct  = (idx >> 10) & 7;
    int n  = g * H + ct * 16 + l15;                      // gate row in [0,512)
    int k0 = kc * 32 + q * 8;
    float s = (g == 2) ? TWOLOG2E : LOG2E;
    const float* src = W_hh + (size_t)n * H + k0;
    f16x8 f;
    #pragma unroll
    for (int i = 0; i < 8; ++i) f[i] = (_Float16)(src[i] * s);
    *(f16x8*)(wfrag + (size_t)idx * 8) = f;
}

__device__ __forceinline__ float frcp(float v)  { return __builtin_amdgcn_rcpf(v); }
__device__ __forceinline__ float fexp2(float v) { return __builtin_amdgcn_exp2f(v); }

// ---- one LSTM step: 16 batches x this wave's 2 column tiles (32 cols) ----
__device__ __forceinline__ void lstm_step(const _Float16* hr, _Float16* hw,
                                          const float* xp,
                                          const f16x8 wf[2][4][4],
                                          const float wihs[2][4], const float biass[2][4],
                                          float c[2][4], int l15, int q, int jc0)
{
    // A-fragments (h data, SHARED by both column tiles): 4x ds_read_b128
    const _Float16* ar = hr + l15 * HSTRIDE + q * 8;
    f16x8 af0 = *(const f16x8*)(ar);
    f16x8 af1 = *(const f16x8*)(ar + 32);
    f16x8 af2 = *(const f16x8*)(ar + 64);
    f16x8 af3 = *(const f16x8*)(ar + 96);

    float4 xl = *(const float4*)xp;     // x for rows b = q*4 + 0..3
    f32x4 acc[2][4];
    #pragma unroll
    for (int ct = 0; ct < 2; ++ct)
        #pragma unroll
        for (int g = 0; g < 4; ++g) {
            f32x4 iv;
            iv[0] = fmaf(xl.x, wihs[ct][g], biass[ct][g]);
            iv[1] = fmaf(xl.y, wihs[ct][g], biass[ct][g]);
            iv[2] = fmaf(xl.z, wihs[ct][g], biass[ct][g]);
            iv[3] = fmaf(xl.w, wihs[ct][g], biass[ct][g]);
            acc[ct][g] = __builtin_amdgcn_mfma_f32_16x16x32_f16(af0, wf[ct][g][0], iv, 0, 0, 0);
        }
    #pragma unroll
    for (int ct = 0; ct < 2; ++ct)
        #pragma unroll
        for (int g = 0; g < 4; ++g)
            acc[ct][g] = __builtin_amdgcn_mfma_f32_16x16x32_f16(af1, wf[ct][g][1], acc[ct][g], 0, 0, 0);
    #pragma unroll
    for (int ct = 0; ct < 2; ++ct)
        #pragma unroll
        for (int g = 0; g < 4; ++g)
            acc[ct][g] = __builtin_amdgcn_mfma_f32_16x16x32_f16(af2, wf[ct][g][2], acc[ct][g], 0, 0, 0);
    #pragma unroll
    for (int ct = 0; ct < 2; ++ct)
        #pragma unroll
        for (int g = 0; g < 4; ++g)
            acc[ct][g] = __builtin_amdgcn_mfma_f32_16x16x32_f16(af3, wf[ct][g][3], acc[ct][g], 0, 0, 0);

    // ---- elementwise per tile (log2 domain, fused-rcp) ----
    #pragma unroll
    for (int ct = 0; ct < 2; ++ct) {
        float Ei[4], Ef[4], Eg[4], Eo[4];
        #pragma unroll
        for (int r = 0; r < 4; ++r) {
            Ei[r] = fexp2(-acc[ct][0][r]);   // sigmoid_i = 1/(1+Ei)
            Ef[r] = fexp2(-acc[ct][1][r]);   // sigmoid_f = 1/(1+Ef)
            Eg[r] = fexp2( acc[ct][2][r]);   // tanh_g    = (Eg-1)/(Eg+1)
            Eo[r] = fexp2(-acc[ct][3][r]);   // sigmoid_o = 1/(1+Eo)
        }
        _Float16* hwp = hw + (q * 4) * HSTRIDE + jc0 + ct * 16;
        #pragma unroll
        for (int r = 0; r < 4; ++r) {
            float u  = 1.0f + Ei[r];
            float v  = 1.0f + Ef[r];
            float w  = 1.0f + Eg[r];
            float wm = Eg[r] - 1.0f;
            float uw = u * w;
            float cn = fmaf(c[ct][r], uw, wm * v) * frcp(v * uw);   // one rcp
            c[ct][r] = cn;
            float Ec = fexp2(cn * TWOLOG2E); // tanh(c') = (Ec-1)/(Ec+1)
            float hv = (Ec - 1.0f) * frcp((Ec + 1.0f) * (1.0f + Eo[r]));
            hwp[r * HSTRIDE] = (_Float16)hv;
        }
    }
}

__launch_bounds__(BLOCK, 2)
__global__ void lstm_fused_kernel(const float* __restrict__ x,
                                  const float* __restrict__ W_ih,
                                  const _Float16* __restrict__ wfrag,
                                  const float* __restrict__ b_ih,
                                  const float* __restrict__ b_hh,
                                  const float* __restrict__ fc_W,
                                  const float* __restrict__ fc_b,
                                  float* __restrict__ out)
{
    __shared__ __align__(16) float xs[T][XSTRIDE];               // 10 KB
    __shared__ __align__(16) _Float16 hb0[16 * HSTRIDE];         // h buffers (4.25 KB each)
    __shared__ __align__(16) _Float16 hb1[16 * HSTRIDE];

    const int tid  = threadIdx.x;
    const int wave = tid >> 6;          // 0..3; owns column tiles 2*wave, 2*wave+1
    const int lane = tid & 63;
    const int l15  = lane & 15;
    const int q    = lane >> 4;         // 0..3
    const int jc0  = wave * 32 + l15;   // first tile's column for this lane

    // ---- stage x: [b][t] global -> xs[t][b] (16 batches x 128 t, 8 vals/thread) ----
    {
        const int t0 = tid & 127;
        const int bb = (tid >> 7) * 8;  // 0 or 8
        const float* xb = x + (size_t)blockIdx.x * (16 * T);
        #pragma unroll
        for (int i = 0; i < 8; ++i)
            xs[t0][bb + i] = xb[(bb + i) * T + t0];
    }
    for (int i = tid; i < 16 * HSTRIDE; i += BLOCK)              // h0 = 0
        hb0[i] = (_Float16)0.0f;

    // ---- weights: this wave's 2 column tiles as f16 fragments (128 VGPRs) ----
    f16x8 wf[2][4][4];
    float wihs[2][4], biass[2][4];
    #pragma unroll
    for (int ct = 0; ct < 2; ++ct) {
        const _Float16* wbase = wfrag + (size_t)(wave * 2 + ct) * 8192;
        #pragma unroll
        for (int g = 0; g < 4; ++g) {
            const int n = g * H + wave * 32 + ct * 16 + l15;
            const float s = (g == 2) ? TWOLOG2E : LOG2E;
            wihs[ct][g]  = W_ih[n] * s;
            biass[ct][g] = (b_ih[n] + b_hh[n]) * s;
            #pragma unroll
            for (int kc = 0; kc < 4; ++kc)
                wf[ct][g][kc] = *(const f16x8*)(wbase + ((((g * 4 + kc) * 4 + q) * 16 + l15) * 8));
        }
    }

    float c[2][4] = {{0.f, 0.f, 0.f, 0.f}, {0.f, 0.f, 0.f, 0.f}};

    __syncthreads();

    const float* xp = &xs[0][q * 4];

    // ---- recurrence: unrolled x2, compile-time buffer bases, 1 barrier/step ----
    #pragma unroll 1
    for (int t2 = 0; t2 < T / 2; ++t2) {
        lstm_step(hb0, hb1, xp, wf, wihs, biass, c, l15, q, jc0);
        xp += XSTRIDE;
        __syncthreads();
        lstm_step(hb1, hb0, xp, wf, wihs, biass, c, l15, q, jc0);
        xp += XSTRIDE;
        __syncthreads();
    }
    // T even -> final h lives in hb0

    // ---- epilogue: out[b] = fc_b + sum_j fc_W[j] * hT[b][j] (256 thr = 16b x 16p) ----
    {
        const int b    = tid >> 4;      // 0..15
        const int part = tid & 15;
        const _Float16* hrow = &hb0[b * HSTRIDE];
        float s = 0.0f;
        #pragma unroll
        for (int i = 0; i < 8; ++i) {
            const int j = part * 8 + i;
            s += fc_W[j] * (float)hrow[j];
        }
        s += __shfl_xor(s, 8, 16);
        s += __shfl_xor(s, 4, 16);
        s += __shfl_xor(s, 2, 16);
        s += __shfl_xor(s, 1, 16);
        if (part == 0)
            out[blockIdx.x * 16 + b] = s + fc_b[0];
    }
}

extern "C" void kernel_launch(void* const* d_in, const int* in_sizes, int n_in,
                              void* d_out, int out_size, void* d_ws, size_t ws_size,
                              hipStream_t stream)
{
    const float* x    = (const float*)d_in[0];
    const float* W_ih = (const float*)d_in[1];
    const float* W_hh = (const float*)d_in[2];
    const float* b_ih = (const float*)d_in[3];
    const float* b_hh = (const float*)d_in[4];
    const float* fc_W = (const float*)d_in[5];
    const float* fc_b = (const float*)d_in[6];
    float* out = (float*)d_out;

    _Float16* wfrag = (_Float16*)d_ws;     // 64K f16 = 128 KB fragment-ordered, log2e-scaled

    hipLaunchKernelGGL(prep_whh_kernel, dim3(32), dim3(256), 0, stream, W_hh, wfrag);

    const int B = in_sizes[0] / H;         // 4096 chunks
    dim3 grid(B / 16);                     // 256 blocks -> 2 blocks/CU (indep barriers)
    dim3 block(BLOCK);                     // 4 waves/block -> 2 waves/SIMD, diff blocks
    hipLaunchKernelGGL(lstm_fused_kernel, grid, block, 0, stream,
                       x, W_ih, wfrag, b_ih, b_hh, fc_W, fc_b, out);
}